// Round 2
// baseline (714.976 us; speedup 1.0000x reference)
//
#include <hip/hip_runtime.h>

typedef short v8s __attribute__((ext_vector_type(8)));   // 8 x bf16 (4 VGPR)
typedef float v4f __attribute__((ext_vector_type(4)));

__device__ __forceinline__ float bf2f(unsigned short u) {
    unsigned v = ((unsigned)u) << 16;
    return __builtin_bit_cast(float, v);
}
__device__ __forceinline__ unsigned short f2bf(float f) {
    unsigned u = __builtin_bit_cast(unsigned, f);
    u += 0x7fffu + ((u >> 16) & 1u);               // RNE
    return (unsigned short)(u >> 16);
}
__device__ __forceinline__ float sigm(float x) {
    float e = __builtin_amdgcn_exp2f(-1.44269504f * x);
    return __builtin_amdgcn_rcpf(1.0f + e);
}
__device__ __forceinline__ float tanh_(float x) {
    float e = __builtin_amdgcn_exp2f(2.88539008f * x);
    return 1.0f - 2.0f * __builtin_amdgcn_rcpf(1.0f + e);
}
__device__ __forceinline__ v4f mfma(v8s a, v8s b, v4f c) {
    return __builtin_amdgcn_mfma_f32_16x16x32_bf16(a, b, c, 0, 0, 0);
}
// B-frag for Z = Xin @ W^T from f32 W: lane holds W[n][k0..k0+7] as bf16.
__device__ __forceinline__ v8s ldwf(const float* W, int rowElems, int n, int k0) {
    const float* p = W + (size_t)n * rowElems + k0;
    v8s r;
    #pragma unroll
    for (int j = 0; j < 8; ++j) r[j] = (short)f2bf(p[j]);
    return r;
}

__global__ __launch_bounds__(256, 2) void seq2seq(
    const float* __restrict__ X,
    const float* __restrict__ bias,
    const float* __restrict__ eWih0, const float* __restrict__ eWhh0, const float* __restrict__ eb0,
    const float* __restrict__ eWih1, const float* __restrict__ eWhh1, const float* __restrict__ eb1,
    const float* __restrict__ dWih0, const float* __restrict__ dWhh0, const float* __restrict__ db0,
    const float* __restrict__ dWih1, const float* __restrict__ dWhh1, const float* __restrict__ db1,
    const float* __restrict__ rW1, const float* __restrict__ rb1,
    const float* __restrict__ rW2, const float* __restrict__ rb2,
    float* __restrict__ out)
{
    // h staging, frag-linear: [parity][part hi/lo][Mt*1024 + kk*512 + lane*8 + j]
    __shared__ __align__(16) short sh0[2][2][2048];
    __shared__ __align__(16) short sh1[2][2][2048];
    __shared__ __align__(16) short sy1[2048];

    const int tid  = threadIdx.x;
    const int lane = tid & 63;
    const int w    = tid >> 6;            // unit-group 0..3 (units 16w..16w+15)
    const int lo   = lane & 15, hi = lane >> 4;
    const int wg   = blockIdx.x;          // 32 batch rows per block

    // zero parity-1 staging (initial h = 0): shorts [4096,8192) = ints [2048,4096)
    for (int i = tid; i < 2048; i += 256) {
        ((int*)sh0)[2048 + i] = 0;
        ((int*)sh1)[2048 + i] = 0;
    }

    // staging write index for value (m = mt*16+hi*4+q, u = 16w+lo):
    // kk = w>>1; p = ((u>>3)&3)*128 + mloc*8 + (u&7)
    const int wsidx = (w >> 1) * 512 + (((2 * w) + (lo >> 3)) & 3) * 128 + hi * 32 + (lo & 7);

    // ---- encoder weights -> register B-frags (f32 -> bf16) ----
    v8s wf[4][4][2];                      // [matrix][gate g (Ntile=w+4g)][kstep]
    float bz0[4], bz1[4];
    #pragma unroll
    for (int g = 0; g < 4; ++g) {
        const int n = (w + 4 * g) * 16 + lo;       // z column (row of W)
        v8s z = {0, 0, 0, 0, 0, 0, 0, 0};
        wf[0][g][0] = (hi < 2) ? ldwf(eWih0, 16, n, (hi & 1) * 8) : z;  // K=16, zero-pad k>=16
        wf[0][g][1] = z;
        #pragma unroll
        for (int kk = 0; kk < 2; ++kk) {
            wf[1][g][kk] = ldwf(eWhh0, 64, n, kk * 32 + hi * 8);
            wf[2][g][kk] = ldwf(eWih1, 64, n, kk * 32 + hi * 8);
            wf[3][g][kk] = ldwf(eWhh1, 64, n, kk * 32 + hi * 8);
        }
        bz0[g] = eb0[g * 64 + w * 16 + lo];
        bz1[g] = eb1[g * 64 + w * 16 + lo];
    }

    float c0[2][4] = {{0.f,0.f,0.f,0.f},{0.f,0.f,0.f,0.f}};
    float c1[2][4] = {{0.f,0.f,0.f,0.f},{0.f,0.f,0.f,0.f}};
    __syncthreads();   // staging zeros visible

    const float* xb = X + (size_t)(wg * 32 + lo) * 1536 + (hi & 1) * 8;

    // ================= encoder =================
    for (int t = 0; t < 96; ++t) {
        const int pw = t & 1, pr = pw ^ 1;
        v4f acc[4][2];
        // ---- layer 0: z = x_t@Wih0^T + h0@Whh0^T + b0 ----
        #pragma unroll
        for (int g = 0; g < 4; ++g)
            #pragma unroll
            for (int mt = 0; mt < 2; ++mt)
                acc[g][mt] = (v4f){bz0[g], bz0[g], bz0[g], bz0[g]};
        #pragma unroll
        for (int mt = 0; mt < 2; ++mt) {
            const float* p = xb + (size_t)mt * 16 * 1536 + t * 16;
            v8s ax;
            #pragma unroll
            for (int j = 0; j < 8; ++j) ax[j] = (short)f2bf(p[j]);
            #pragma unroll
            for (int g = 0; g < 4; ++g) acc[g][mt] = mfma(ax, wf[0][g][0], acc[g][mt]);
        }
        #pragma unroll
        for (int kk = 0; kk < 2; ++kk)
            #pragma unroll
            for (int mt = 0; mt < 2; ++mt) {
                const v8s ah = *(const v8s*)&sh0[pr][0][(mt * 2 + kk) * 512 + lane * 8];
                const v8s al = *(const v8s*)&sh0[pr][1][(mt * 2 + kk) * 512 + lane * 8];
                #pragma unroll
                for (int g = 0; g < 4; ++g) {
                    acc[g][mt] = mfma(ah, wf[1][g][kk], acc[g][mt]);
                    acc[g][mt] = mfma(al, wf[1][g][kk], acc[g][mt]);
                }
            }
        #pragma unroll
        for (int mt = 0; mt < 2; ++mt)
            #pragma unroll
            for (int q = 0; q < 4; ++q) {
                float cc = sigm(acc[1][mt][q]) * c0[mt][q] + sigm(acc[0][mt][q]) * tanh_(acc[2][mt][q]);
                c0[mt][q] = cc;
                float h = sigm(acc[3][mt][q]) * tanh_(cc);
                unsigned short uh = f2bf(h);
                sh0[pw][0][wsidx + mt * 1024 + q * 8] = (short)uh;
                sh0[pw][1][wsidx + mt * 1024 + q * 8] = (short)f2bf(h - bf2f(uh));
            }
        __syncthreads();
        // ---- layer 1: z = h0@Wih1^T + h1@Whh1^T + b1 ----
        #pragma unroll
        for (int g = 0; g < 4; ++g)
            #pragma unroll
            for (int mt = 0; mt < 2; ++mt)
                acc[g][mt] = (v4f){bz1[g], bz1[g], bz1[g], bz1[g]};
        #pragma unroll
        for (int kk = 0; kk < 2; ++kk)
            #pragma unroll
            for (int mt = 0; mt < 2; ++mt) {
                const v8s ah = *(const v8s*)&sh0[pw][0][(mt * 2 + kk) * 512 + lane * 8];
                const v8s al = *(const v8s*)&sh0[pw][1][(mt * 2 + kk) * 512 + lane * 8];
                const v8s bh = *(const v8s*)&sh1[pr][0][(mt * 2 + kk) * 512 + lane * 8];
                const v8s bl = *(const v8s*)&sh1[pr][1][(mt * 2 + kk) * 512 + lane * 8];
                #pragma unroll
                for (int g = 0; g < 4; ++g) {
                    acc[g][mt] = mfma(ah, wf[2][g][kk], acc[g][mt]);
                    acc[g][mt] = mfma(al, wf[2][g][kk], acc[g][mt]);
                    acc[g][mt] = mfma(bh, wf[3][g][kk], acc[g][mt]);
                    acc[g][mt] = mfma(bl, wf[3][g][kk], acc[g][mt]);
                }
            }
        #pragma unroll
        for (int mt = 0; mt < 2; ++mt)
            #pragma unroll
            for (int q = 0; q < 4; ++q) {
                float cc = sigm(acc[1][mt][q]) * c1[mt][q] + sigm(acc[0][mt][q]) * tanh_(acc[2][mt][q]);
                c1[mt][q] = cc;
                float h = sigm(acc[3][mt][q]) * tanh_(cc);
                unsigned short uh = f2bf(h);
                sh1[pw][0][wsidx + mt * 1024 + q * 8] = (short)uh;
                sh1[pw][1][wsidx + mt * 1024 + q * 8] = (short)f2bf(h - bf2f(uh));
            }
        __syncthreads();
    }
    // finals (t=95, pw=1): h0 in sh0[1], h1 in sh1[1]

    // ---- decoder + head weights -> registers ----
    #pragma unroll
    for (int g = 0; g < 4; ++g) {
        const int n = (w + 4 * g) * 16 + lo;
        #pragma unroll
        for (int kk = 0; kk < 2; ++kk) {
            wf[0][g][kk] = ldwf(dWih0, 64, n, kk * 32 + hi * 8);
            wf[1][g][kk] = ldwf(dWhh0, 64, n, kk * 32 + hi * 8);
            wf[2][g][kk] = ldwf(dWih1, 64, n, kk * 32 + hi * 8);
            wf[3][g][kk] = ldwf(dWhh1, 64, n, kk * 32 + hi * 8);
        }
        bz0[g] = db0[g * 64 + w * 16 + lo];
        bz1[g] = db1[g * 64 + w * 16 + lo];
    }
    v8s w1f[2], w2f[2];
    #pragma unroll
    for (int kk = 0; kk < 2; ++kk) {
        w1f[kk] = ldwf(rW1, 64, w * 16 + lo, kk * 32 + hi * 8);
        w2f[kk] = ldwf(rW2, 64, lo, kk * 32 + hi * 8);
    }
    const float hb1 = rb1[w * 16 + lo];
    const float hb2 = rb2[lo];
    float lb[2][4];
    #pragma unroll
    for (int mt = 0; mt < 2; ++mt)
        #pragma unroll
        for (int q = 0; q < 4; ++q) {
            lb[mt][q] = bias[(size_t)(wg * 32 + mt * 16 + hi * 4 + q) * 16 + lo];
            c0[mt][q] = 0.f;
            c1[mt][q] = 0.f;
        }

    // ================= decoder =================
    for (int s = 0; s < 24; ++s) {
        const int pw = s & 1, pr = pw ^ 1;   // s=0 reads parity 1 = encoder finals
        v4f acc[4][2];
        // ---- dec layer 0: x = h_t (sh1[pr]), hidden = dh0 (sh0[pr]) -> sh0[pw] ----
        #pragma unroll
        for (int g = 0; g < 4; ++g)
            #pragma unroll
            for (int mt = 0; mt < 2; ++mt)
                acc[g][mt] = (v4f){bz0[g], bz0[g], bz0[g], bz0[g]};
        #pragma unroll
        for (int kk = 0; kk < 2; ++kk)
            #pragma unroll
            for (int mt = 0; mt < 2; ++mt) {
                const v8s ah = *(const v8s*)&sh1[pr][0][(mt * 2 + kk) * 512 + lane * 8];
                const v8s al = *(const v8s*)&sh1[pr][1][(mt * 2 + kk) * 512 + lane * 8];
                const v8s bh = *(const v8s*)&sh0[pr][0][(mt * 2 + kk) * 512 + lane * 8];
                const v8s bl = *(const v8s*)&sh0[pr][1][(mt * 2 + kk) * 512 + lane * 8];
                #pragma unroll
                for (int g = 0; g < 4; ++g) {
                    acc[g][mt] = mfma(ah, wf[0][g][kk], acc[g][mt]);
                    acc[g][mt] = mfma(al, wf[0][g][kk], acc[g][mt]);
                    acc[g][mt] = mfma(bh, wf[1][g][kk], acc[g][mt]);
                    acc[g][mt] = mfma(bl, wf[1][g][kk], acc[g][mt]);
                }
            }
        #pragma unroll
        for (int mt = 0; mt < 2; ++mt)
            #pragma unroll
            for (int q = 0; q < 4; ++q) {
                float cc = sigm(acc[1][mt][q]) * c0[mt][q] + sigm(acc[0][mt][q]) * tanh_(acc[2][mt][q]);
                c0[mt][q] = cc;
                float h = sigm(acc[3][mt][q]) * tanh_(cc);
                unsigned short uh = f2bf(h);
                sh0[pw][0][wsidx + mt * 1024 + q * 8] = (short)uh;
                sh0[pw][1][wsidx + mt * 1024 + q * 8] = (short)f2bf(h - bf2f(uh));
            }
        __syncthreads();
        // ---- dec layer 1: x = sh0[pw], hidden = dh1 (sh1[pr]) -> sh1[pw] ----
        #pragma unroll
        for (int g = 0; g < 4; ++g)
            #pragma unroll
            for (int mt = 0; mt < 2; ++mt)
                acc[g][mt] = (v4f){bz1[g], bz1[g], bz1[g], bz1[g]};
        #pragma unroll
        for (int kk = 0; kk < 2; ++kk)
            #pragma unroll
            for (int mt = 0; mt < 2; ++mt) {
                const v8s ah = *(const v8s*)&sh0[pw][0][(mt * 2 + kk) * 512 + lane * 8];
                const v8s al = *(const v8s*)&sh0[pw][1][(mt * 2 + kk) * 512 + lane * 8];
                const v8s bh = *(const v8s*)&sh1[pr][0][(mt * 2 + kk) * 512 + lane * 8];
                const v8s bl = *(const v8s*)&sh1[pr][1][(mt * 2 + kk) * 512 + lane * 8];
                #pragma unroll
                for (int g = 0; g < 4; ++g) {
                    acc[g][mt] = mfma(ah, wf[2][g][kk], acc[g][mt]);
                    acc[g][mt] = mfma(al, wf[2][g][kk], acc[g][mt]);
                    acc[g][mt] = mfma(bh, wf[3][g][kk], acc[g][mt]);
                    acc[g][mt] = mfma(bl, wf[3][g][kk], acc[g][mt]);
                }
            }
        #pragma unroll
        for (int mt = 0; mt < 2; ++mt)
            #pragma unroll
            for (int q = 0; q < 4; ++q) {
                float cc = sigm(acc[1][mt][q]) * c1[mt][q] + sigm(acc[0][mt][q]) * tanh_(acc[2][mt][q]);
                c1[mt][q] = cc;
                float h = sigm(acc[3][mt][q]) * tanh_(cc);
                unsigned short uh = f2bf(h);
                sh1[pw][0][wsidx + mt * 1024 + q * 8] = (short)uh;
                sh1[pw][1][wsidx + mt * 1024 + q * 8] = (short)f2bf(h - bf2f(uh));
            }
        __syncthreads();
        // ---- head GEMM1: y1 = relu(h_t @ W1^T + b1), Ntile = w ----
        v4f ay[2];
        #pragma unroll
        for (int mt = 0; mt < 2; ++mt) ay[mt] = (v4f){hb1, hb1, hb1, hb1};
        #pragma unroll
        for (int kk = 0; kk < 2; ++kk)
            #pragma unroll
            for (int mt = 0; mt < 2; ++mt) {
                const v8s ah = *(const v8s*)&sh1[pw][0][(mt * 2 + kk) * 512 + lane * 8];
                const v8s al = *(const v8s*)&sh1[pw][1][(mt * 2 + kk) * 512 + lane * 8];
                ay[mt] = mfma(ah, w1f[kk], ay[mt]);
                ay[mt] = mfma(al, w1f[kk], ay[mt]);
            }
        #pragma unroll
        for (int mt = 0; mt < 2; ++mt)
            #pragma unroll
            for (int q = 0; q < 4; ++q)
                sy1[wsidx + mt * 1024 + q * 8] = (short)f2bf(fmaxf(ay[mt][q], 0.f));
        __syncthreads();
        // ---- head GEMM2 (N=16): wave w==0 only ----
        if (w == 0) {
            v4f a2[2];
            #pragma unroll
            for (int mt = 0; mt < 2; ++mt) a2[mt] = (v4f){hb2, hb2, hb2, hb2};
            #pragma unroll
            for (int kk = 0; kk < 2; ++kk)
                #pragma unroll
                for (int mt = 0; mt < 2; ++mt) {
                    const v8s a = *(const v8s*)&sy1[(mt * 2 + kk) * 512 + lane * 8];
                    a2[mt] = mfma(a, w2f[kk], a2[mt]);
                }
            #pragma unroll
            for (int mt = 0; mt < 2; ++mt)
                #pragma unroll
                for (int q = 0; q < 4; ++q) {
                    size_t row = (size_t)(wg * 32 + mt * 16 + hi * 4 + q);
                    out[row * 384 + s * 16 + lo] = a2[mt][q] + lb[mt][q];
                }
        }
    }
}

extern "C" void kernel_launch(void* const* d_in, const int* in_sizes, int n_in,
                              void* d_out, int out_size, void* d_ws, size_t ws_size,
                              hipStream_t stream) {
    seq2seq<<<dim3(512), dim3(256), 0, stream>>>(
        (const float*)d_in[0],   // X
        (const float*)d_in[1],   // bias   (d_in[2] = X_mask, unused by reference)
        (const float*)d_in[3],  (const float*)d_in[4],  (const float*)d_in[5],
        (const float*)d_in[6],  (const float*)d_in[7],  (const float*)d_in[8],
        (const float*)d_in[9],  (const float*)d_in[10], (const float*)d_in[11],
        (const float*)d_in[12], (const float*)d_in[13], (const float*)d_in[14],
        (const float*)d_in[15], (const float*)d_in[16],
        (const float*)d_in[17], (const float*)d_in[18],
        (float*)d_out);
}

// Round 4
// 616.382 us; speedup vs baseline: 1.1600x; 1.1600x over previous
//
#include <hip/hip_runtime.h>

typedef short v8s __attribute__((ext_vector_type(8)));   // 8 x bf16 (4 VGPR)
typedef float v4f __attribute__((ext_vector_type(4)));

__device__ __forceinline__ unsigned short f2bf(float f) {
    unsigned u = __builtin_bit_cast(unsigned, f);
    u += 0x7fffu + ((u >> 16) & 1u);               // RNE
    return (unsigned short)(u >> 16);
}
__device__ __forceinline__ unsigned pk2(float a, float b) {
    return (unsigned)f2bf(a) | ((unsigned)f2bf(b) << 16);
}
__device__ __forceinline__ v8s pack8(float4 f0, float4 f1) {
    union { unsigned u[4]; v8s v; } r;
    r.u[0] = pk2(f0.x, f0.y); r.u[1] = pk2(f0.z, f0.w);
    r.u[2] = pk2(f1.x, f1.y); r.u[3] = pk2(f1.z, f1.w);
    return r.v;
}
__device__ __forceinline__ float sigm(float x) {
    float e = __builtin_amdgcn_exp2f(-1.44269504f * x);
    return __builtin_amdgcn_rcpf(1.0f + e);
}
__device__ __forceinline__ float tanh_(float x) {
    float e = __builtin_amdgcn_exp2f(2.88539008f * x);
    return 1.0f - 2.0f * __builtin_amdgcn_rcpf(1.0f + e);
}
__device__ __forceinline__ v4f mfma(v8s a, v8s b, v4f c) {
    return __builtin_amdgcn_mfma_f32_16x16x32_bf16(a, b, c, 0, 0, 0);
}
// B-frag for Z = Xin @ W^T from f32 W: lane holds W[n][k0..k0+7] as bf16.
__device__ __forceinline__ v8s ldwf(const float* W, int rowElems, int n, int k0) {
    const float* p = W + (size_t)n * rowElems + k0;
    v8s r;
    #pragma unroll
    for (int j = 0; j < 8; ++j) r[j] = (short)f2bf(p[j]);
    return r;
}

__global__ __launch_bounds__(256, 2) void seq2seq(
    const float* __restrict__ X,
    const float* __restrict__ bias,
    const float* __restrict__ eWih0, const float* __restrict__ eWhh0, const float* __restrict__ eb0,
    const float* __restrict__ eWih1, const float* __restrict__ eWhh1, const float* __restrict__ eb1,
    const float* __restrict__ dWih0, const float* __restrict__ dWhh0, const float* __restrict__ db0,
    const float* __restrict__ dWih1, const float* __restrict__ dWhh1, const float* __restrict__ db1,
    const float* __restrict__ rW1, const float* __restrict__ rb1,
    const float* __restrict__ rW2, const float* __restrict__ rb2,
    float* __restrict__ out)
{
    // h staging, frag-linear: [parity][(mt*2+kk)*512 + lane*8 + j], bf16 single-plane
    __shared__ __align__(16) short sh0[2][2048];
    __shared__ __align__(16) short sh1[2][2048];
    __shared__ __align__(16) short sy1[2048];

    const int tid  = threadIdx.x;
    const int lane = tid & 63;
    const int w    = tid >> 6;            // unit-group 0..3 (units 16w..16w+15)
    const int lo   = lane & 15, hi = lane >> 4;
    const int wg   = blockIdx.x;          // 32 batch rows per block

    // zero parity-1 staging (initial h = 0): shorts [2048,4096) = ints [1024,2048)
    for (int i = tid; i < 1024; i += 256) {
        ((int*)sh0)[1024 + i] = 0;
        ((int*)sh1)[1024 + i] = 0;
    }

    // staging write index for value (m = mt*16+hi*4+q, u = 16w+lo):
    const int wsidx = (w >> 1) * 512 + (((2 * w) + (lo >> 3)) & 3) * 128 + hi * 32 + (lo & 7);

    // ---- encoder weights -> register B-frags (f32 -> bf16) ----
    v8s wf[4][4][2];                      // [matrix][gate g (Ntile=w+4g)][kstep]
    float bz0[4], bz1[4];
    #pragma unroll
    for (int g = 0; g < 4; ++g) {
        const int n = (w + 4 * g) * 16 + lo;       // z column (row of W)
        v8s z = {0, 0, 0, 0, 0, 0, 0, 0};
        wf[0][g][0] = (hi < 2) ? ldwf(eWih0, 16, n, (hi & 1) * 8) : z;  // K=16, zero-pad k>=16
        wf[0][g][1] = z;
        #pragma unroll
        for (int kk = 0; kk < 2; ++kk) {
            wf[1][g][kk] = ldwf(eWhh0, 64, n, kk * 32 + hi * 8);
            wf[2][g][kk] = ldwf(eWih1, 64, n, kk * 32 + hi * 8);
            wf[3][g][kk] = ldwf(eWhh1, 64, n, kk * 32 + hi * 8);
        }
        bz0[g] = eb0[g * 64 + w * 16 + lo];
        bz1[g] = eb1[g * 64 + w * 16 + lo];
    }

    float c0[2][4] = {{0.f,0.f,0.f,0.f},{0.f,0.f,0.f,0.f}};
    float c1[2][4] = {{0.f,0.f,0.f,0.f},{0.f,0.f,0.f,0.f}};
    __syncthreads();   // staging zeros visible

    const float* xb = X + (size_t)(wg * 32 + lo) * 1536 + (hi & 1) * 8;

    // ================= encoder (ONE barrier per step) =================
    for (int t = 0; t < 96; ++t) {
        const int pw = t & 1, pr = pw ^ 1;
        v4f acc[4][2];
        // ---- layer 0: z = x_t@Wih0^T + h0@Whh0^T + b0 ----
        #pragma unroll
        for (int g = 0; g < 4; ++g)
            #pragma unroll
            for (int mt = 0; mt < 2; ++mt)
                acc[g][mt] = (v4f){bz0[g], bz0[g], bz0[g], bz0[g]};
        #pragma unroll
        for (int mt = 0; mt < 2; ++mt) {
            const float* p = xb + (size_t)mt * 16 * 1536 + t * 16;
            const v8s ax = pack8(*(const float4*)p, *(const float4*)(p + 4));
            #pragma unroll
            for (int g = 0; g < 4; ++g) acc[g][mt] = mfma(ax, wf[0][g][0], acc[g][mt]);
        }
        #pragma unroll
        for (int kk = 0; kk < 2; ++kk)
            #pragma unroll
            for (int mt = 0; mt < 2; ++mt) {
                const v8s ah = *(const v8s*)&sh0[pr][(mt * 2 + kk) * 512 + lane * 8];
                #pragma unroll
                for (int g = 0; g < 4; ++g) acc[g][mt] = mfma(ah, wf[1][g][kk], acc[g][mt]);
            }
        #pragma unroll
        for (int mt = 0; mt < 2; ++mt) {
            float hh[4];
            #pragma unroll
            for (int q = 0; q < 4; ++q) {
                float cc = sigm(acc[1][mt][q]) * c0[mt][q] + sigm(acc[0][mt][q]) * tanh_(acc[2][mt][q]);
                c0[mt][q] = cc;
                hh[q] = sigm(acc[3][mt][q]) * tanh_(cc);
            }
            #pragma unroll
            for (int qp = 0; qp < 2; ++qp) {
                unsigned pk = pk2(hh[2 * qp], hh[2 * qp + 1]);
                short* b = &sh0[pw][wsidx + mt * 1024 + qp * 16];
                b[0] = (short)pk; b[8] = (short)(pk >> 16);
            }
        }
        __syncthreads();
        // ---- layer 1: z = h0@Wih1^T + h1@Whh1^T + b1 ----
        #pragma unroll
        for (int g = 0; g < 4; ++g)
            #pragma unroll
            for (int mt = 0; mt < 2; ++mt)
                acc[g][mt] = (v4f){bz1[g], bz1[g], bz1[g], bz1[g]};
        #pragma unroll
        for (int kk = 0; kk < 2; ++kk)
            #pragma unroll
            for (int mt = 0; mt < 2; ++mt) {
                const v8s ah = *(const v8s*)&sh0[pw][(mt * 2 + kk) * 512 + lane * 8];
                const v8s bh = *(const v8s*)&sh1[pr][(mt * 2 + kk) * 512 + lane * 8];
                #pragma unroll
                for (int g = 0; g < 4; ++g) {
                    acc[g][mt] = mfma(ah, wf[2][g][kk], acc[g][mt]);
                    acc[g][mt] = mfma(bh, wf[3][g][kk], acc[g][mt]);
                }
            }
        #pragma unroll
        for (int mt = 0; mt < 2; ++mt) {
            float hh[4];
            #pragma unroll
            for (int q = 0; q < 4; ++q) {
                float cc = sigm(acc[1][mt][q]) * c1[mt][q] + sigm(acc[0][mt][q]) * tanh_(acc[2][mt][q]);
                c1[mt][q] = cc;
                hh[q] = sigm(acc[3][mt][q]) * tanh_(cc);
            }
            #pragma unroll
            for (int qp = 0; qp < 2; ++qp) {
                unsigned pk = pk2(hh[2 * qp], hh[2 * qp + 1]);
                short* b = &sh1[pw][wsidx + mt * 1024 + qp * 16];
                b[0] = (short)pk; b[8] = (short)(pk >> 16);
            }
        }
        // no second barrier: next l0 writes sh0[pr] (disjoint from sh0[pw]/sh1[*]
        // read in l1); all cross-wave producer->consumer pairs are ordered by the
        // mid-step barrier of the following step.
    }
    __syncthreads();   // order enc t=95 l1 writes (sh1[1]) before dec s=0 reads
    // finals: h0 in sh0[1], h1 in sh1[1]

    // ---- decoder + head weights -> registers ----
    #pragma unroll
    for (int g = 0; g < 4; ++g) {
        const int n = (w + 4 * g) * 16 + lo;
        #pragma unroll
        for (int kk = 0; kk < 2; ++kk) {
            wf[0][g][kk] = ldwf(dWih0, 64, n, kk * 32 + hi * 8);
            wf[1][g][kk] = ldwf(dWhh0, 64, n, kk * 32 + hi * 8);
            wf[2][g][kk] = ldwf(dWih1, 64, n, kk * 32 + hi * 8);
            wf[3][g][kk] = ldwf(dWhh1, 64, n, kk * 32 + hi * 8);
        }
        bz0[g] = db0[g * 64 + w * 16 + lo];
        bz1[g] = db1[g * 64 + w * 16 + lo];
    }
    v8s w1f[2], w2f[2];
    #pragma unroll
    for (int kk = 0; kk < 2; ++kk) {
        w1f[kk] = ldwf(rW1, 64, w * 16 + lo, kk * 32 + hi * 8);
        w2f[kk] = ldwf(rW2, 64, lo, kk * 32 + hi * 8);
    }
    const float hb1 = rb1[w * 16 + lo];
    const float hb2 = rb2[lo];
    float lb[2][4];
    #pragma unroll
    for (int mt = 0; mt < 2; ++mt)
        #pragma unroll
        for (int q = 0; q < 4; ++q) {
            lb[mt][q] = bias[(size_t)(wg * 32 + mt * 16 + hi * 4 + q) * 16 + lo];
            c0[mt][q] = 0.f;
            c1[mt][q] = 0.f;
        }

    // ================= decoder =================
    for (int s = 0; s < 24; ++s) {
        const int pw = s & 1, pr = pw ^ 1;   // s=0 reads parity 1 = encoder finals
        v4f acc[4][2];
        // ---- dec layer 0: x = h_t (sh1[pr]), hidden = dh0 (sh0[pr]) -> sh0[pw] ----
        #pragma unroll
        for (int g = 0; g < 4; ++g)
            #pragma unroll
            for (int mt = 0; mt < 2; ++mt)
                acc[g][mt] = (v4f){bz0[g], bz0[g], bz0[g], bz0[g]};
        #pragma unroll
        for (int kk = 0; kk < 2; ++kk)
            #pragma unroll
            for (int mt = 0; mt < 2; ++mt) {
                const v8s ah = *(const v8s*)&sh1[pr][(mt * 2 + kk) * 512 + lane * 8];
                const v8s bh = *(const v8s*)&sh0[pr][(mt * 2 + kk) * 512 + lane * 8];
                #pragma unroll
                for (int g = 0; g < 4; ++g) {
                    acc[g][mt] = mfma(ah, wf[0][g][kk], acc[g][mt]);
                    acc[g][mt] = mfma(bh, wf[1][g][kk], acc[g][mt]);
                }
            }
        #pragma unroll
        for (int mt = 0; mt < 2; ++mt) {
            float hh[4];
            #pragma unroll
            for (int q = 0; q < 4; ++q) {
                float cc = sigm(acc[1][mt][q]) * c0[mt][q] + sigm(acc[0][mt][q]) * tanh_(acc[2][mt][q]);
                c0[mt][q] = cc;
                hh[q] = sigm(acc[3][mt][q]) * tanh_(cc);
            }
            #pragma unroll
            for (int qp = 0; qp < 2; ++qp) {
                unsigned pk = pk2(hh[2 * qp], hh[2 * qp + 1]);
                short* b = &sh0[pw][wsidx + mt * 1024 + qp * 16];
                b[0] = (short)pk; b[8] = (short)(pk >> 16);
            }
        }
        __syncthreads();
        // ---- dec layer 1: x = sh0[pw], hidden = dh1 (sh1[pr]) -> sh1[pw] ----
        #pragma unroll
        for (int g = 0; g < 4; ++g)
            #pragma unroll
            for (int mt = 0; mt < 2; ++mt)
                acc[g][mt] = (v4f){bz1[g], bz1[g], bz1[g], bz1[g]};
        #pragma unroll
        for (int kk = 0; kk < 2; ++kk)
            #pragma unroll
            for (int mt = 0; mt < 2; ++mt) {
                const v8s ah = *(const v8s*)&sh0[pw][(mt * 2 + kk) * 512 + lane * 8];
                const v8s bh = *(const v8s*)&sh1[pr][(mt * 2 + kk) * 512 + lane * 8];
                #pragma unroll
                for (int g = 0; g < 4; ++g) {
                    acc[g][mt] = mfma(ah, wf[2][g][kk], acc[g][mt]);
                    acc[g][mt] = mfma(bh, wf[3][g][kk], acc[g][mt]);
                }
            }
        #pragma unroll
        for (int mt = 0; mt < 2; ++mt) {
            float hh[4];
            #pragma unroll
            for (int q = 0; q < 4; ++q) {
                float cc = sigm(acc[1][mt][q]) * c1[mt][q] + sigm(acc[0][mt][q]) * tanh_(acc[2][mt][q]);
                c1[mt][q] = cc;
                hh[q] = sigm(acc[3][mt][q]) * tanh_(cc);
            }
            #pragma unroll
            for (int qp = 0; qp < 2; ++qp) {
                unsigned pk = pk2(hh[2 * qp], hh[2 * qp + 1]);
                short* b = &sh1[pw][wsidx + mt * 1024 + qp * 16];
                b[0] = (short)pk; b[8] = (short)(pk >> 16);
            }
        }
        __syncthreads();
        // ---- head GEMM1: y1 = relu(h_t @ W1^T + b1), Ntile = w ----
        v4f ay[2];
        #pragma unroll
        for (int mt = 0; mt < 2; ++mt) ay[mt] = (v4f){hb1, hb1, hb1, hb1};
        #pragma unroll
        for (int kk = 0; kk < 2; ++kk)
            #pragma unroll
            for (int mt = 0; mt < 2; ++mt) {
                const v8s ah = *(const v8s*)&sh1[pw][(mt * 2 + kk) * 512 + lane * 8];
                ay[mt] = mfma(ah, w1f[kk], ay[mt]);
            }
        #pragma unroll
        for (int mt = 0; mt < 2; ++mt) {
            #pragma unroll
            for (int qp = 0; qp < 2; ++qp) {
                unsigned pk = pk2(fmaxf(ay[mt][2 * qp], 0.f), fmaxf(ay[mt][2 * qp + 1], 0.f));
                short* b = &sy1[wsidx + mt * 1024 + qp * 16];
                b[0] = (short)pk; b[8] = (short)(pk >> 16);
            }
        }
        __syncthreads();
        // ---- head GEMM2 (N=16): wave w==0 only ----
        if (w == 0) {
            v4f a2[2];
            #pragma unroll
            for (int mt = 0; mt < 2; ++mt) a2[mt] = (v4f){hb2, hb2, hb2, hb2};
            #pragma unroll
            for (int kk = 0; kk < 2; ++kk)
                #pragma unroll
                for (int mt = 0; mt < 2; ++mt) {
                    const v8s a = *(const v8s*)&sy1[(mt * 2 + kk) * 512 + lane * 8];
                    a2[mt] = mfma(a, w2f[kk], a2[mt]);
                }
            #pragma unroll
            for (int mt = 0; mt < 2; ++mt)
                #pragma unroll
                for (int q = 0; q < 4; ++q) {
                    size_t row = (size_t)(wg * 32 + mt * 16 + hi * 4 + q);
                    out[row * 384 + s * 16 + lo] = a2[mt][q] + lb[mt][q];
                }
        }
    }
}

extern "C" void kernel_launch(void* const* d_in, const int* in_sizes, int n_in,
                              void* d_out, int out_size, void* d_ws, size_t ws_size,
                              hipStream_t stream) {
    seq2seq<<<dim3(512), dim3(256), 0, stream>>>(
        (const float*)d_in[0],   // X
        (const float*)d_in[1],   // bias   (d_in[2] = X_mask, unused by reference)
        (const float*)d_in[3],  (const float*)d_in[4],  (const float*)d_in[5],
        (const float*)d_in[6],  (const float*)d_in[7],  (const float*)d_in[8],
        (const float*)d_in[9],  (const float*)d_in[10], (const float*)d_in[11],
        (const float*)d_in[12], (const float*)d_in[13], (const float*)d_in[14],
        (const float*)d_in[15], (const float*)d_in[16],
        (const float*)d_in[17], (const float*)d_in[18],
        (float*)d_out);
}